// Round 8
// baseline (446.590 us; speedup 1.0000x reference)
//
#include <hip/hip_runtime.h>
#include <hip/hip_bf16.h>

typedef __attribute__((ext_vector_type(4))) float f32x4;
typedef __attribute__((ext_vector_type(16))) float f32x16;
typedef __attribute__((ext_vector_type(8))) short bf16x8;

__device__ __forceinline__ unsigned short f2bf(float f) {
    return __bfloat16_as_ushort(__float2bfloat16(f));
}

typedef __attribute__((address_space(1))) const unsigned char* gas_ptr;
typedef __attribute__((address_space(3))) unsigned char* las_ptr;
__device__ __forceinline__ void gload16(const void* g, void* l) {
    __builtin_amdgcn_global_load_lds((gas_ptr)g, (las_ptr)l, 16, 0, 0);
}

__device__ __forceinline__ unsigned cvt_pk_bf16(float lo, float hi) {
    unsigned r;
    asm("v_cvt_pk_bf16_f32 %0, %1, %2" : "=v"(r) : "v"(lo), "v"(hi));
    return r;
}

// ---------------- LayerNorm: fp32 in -> bf16 out -------------------
__global__ __launch_bounds__(256) void ln_kernel(
    const float* __restrict__ x, const float* __restrict__ scale,
    const float* __restrict__ bias, unsigned short* __restrict__ out)
{
    int row = blockIdx.x;
    const float* xr = x + (size_t)row * 1024;
    int t = threadIdx.x;
    float4 v = ((const float4*)xr)[t];
    float s  = v.x + v.y + v.z + v.w;
    float ss = v.x*v.x + v.y*v.y + v.z*v.z + v.w*v.w;
    #pragma unroll
    for (int m = 32; m; m >>= 1) { s += __shfl_down(s, m); ss += __shfl_down(ss, m); }
    __shared__ float red[8];
    int wid = t >> 6;
    if ((t & 63) == 0) { red[wid*2] = s; red[wid*2+1] = ss; }
    __syncthreads();
    s  = red[0] + red[2] + red[4] + red[6];
    ss = red[1] + red[3] + red[5] + red[7];
    float mu  = s * (1.0f/1024.0f);
    float var = ss * (1.0f/1024.0f) - mu*mu;
    float inv = rsqrtf(var + 1e-6f);
    float4 sc = ((const float4*)scale)[t];
    float4 bi = ((const float4*)bias)[t];
    ushort4 o;
    o.x = f2bf((v.x - mu)*inv*sc.x + bi.x);
    o.y = f2bf((v.y - mu)*inv*sc.y + bi.y);
    o.z = f2bf((v.z - mu)*inv*sc.z + bi.z);
    o.w = f2bf((v.w - mu)*inv*sc.w + bi.w);
    ((ushort4*)(out + (size_t)row * 1024))[t] = o;
}

// ---------------- Weight transpose: fp32 [K][N] -> bf16 [N][K] -----
__global__ __launch_bounds__(256) void transpose_kernel(
    const float* __restrict__ W, unsigned short* __restrict__ Wt, int K, int N)
{
    __shared__ float tile[32][33];
    int n0 = blockIdx.x * 32, k0 = blockIdx.y * 32;
    int tx = threadIdx.x, ty = threadIdx.y;
    #pragma unroll
    for (int j = 0; j < 32; j += 8)
        tile[ty + j][tx] = W[(size_t)(k0 + ty + j) * N + n0 + tx];
    __syncthreads();
    #pragma unroll
    for (int j = 0; j < 32; j += 8)
        Wt[(size_t)(n0 + ty + j) * K + k0 + tx] = f2bf(tile[tx][ty + j]);
}

// ------- GEMM 256x128 tile, swizzled LDS, TRIPLE-buffer counted vmcnt ----
// C = A[M,K](bf16) @ Bt[N,K](bf16)^T + bias
// Pipeline: stage(t+2) issued at top of iter t; at bottom wait vmcnt(6)
// (= tile t+1's 6 loads done, tile t+2's 6 still in flight across barrier).
template<int EPI>
__global__ __launch_bounds__(512, 2) void gemm256_kernel(
    const unsigned short* __restrict__ A,
    const unsigned short* __restrict__ Bt,
    const float* __restrict__ bias,
    const float* __restrict__ res,
    void* __restrict__ out,
    unsigned short* __restrict__ vtout,
    int M, int N, int K)
{
    constexpr int BM = 256;
    constexpr int BN = 128;

    __shared__ __align__(16) unsigned short Al[3][BM * 64];
    __shared__ __align__(16) unsigned short Bl[3][BN * 64];

    int t = threadIdx.x;
    int wid = t >> 6, lane = t & 63;
    int wr = wid >> 1, wc = wid & 1;      // 4M x 2N waves, WM=64 WN=64
    int l15 = lane & 15, lg = lane >> 4;

    int gx = gridDim.x;
    int nwg = gx * gridDim.y;
    int orig = blockIdx.y * gx + blockIdx.x;
    int cpx = nwg >> 3;
    int wg = (orig & 7) * cpx + (orig >> 3);
    int bx = wg % gx, by = wg / gx;
    int brow = by * BM, bcol = bx * BN;

    f32x4 acc[4][4] = {};

    // staging: thread t covers LDS linear bytes t*16 of each 8 KB slab (64 rows)
    int sr  = t >> 3;                       // row within slab
    int scb = (t & 7) * 16;                 // byte col
    int sce = (scb ^ ((sr & 7) << 4)) >> 1; // pre-swizzled source col (elements)
    const size_t aoff = (size_t)(brow + sr) * K + sce;
    const size_t boff = (size_t)(bcol + sr) * K + sce;

    auto stage = [&](int b, int kt2) {
        int k0 = kt2 << 6;
        char* la = (char*)Al[b] + (wid << 10);
        char* lb = (char*)Bl[b] + (wid << 10);
        #pragma unroll
        for (int i = 0; i < 4; i++)
            gload16(A + aoff + (size_t)(i * 64) * K + k0, la + i * 8192);
        #pragma unroll
        for (int j = 0; j < 2; j++)
            gload16(Bt + boff + (size_t)(j * 64) * K + k0, lb + j * 8192);
    };

    int nk = K >> 6;   // >= 16 for all our shapes
    stage(0, 0);
    __builtin_amdgcn_sched_barrier(0);   // keep the two prologue groups ordered
    stage(1, 1);
    asm volatile("s_waitcnt vmcnt(6)" ::: "memory");   // tile 0 landed; tile 1 in flight
    __builtin_amdgcn_s_barrier();

    int rsw = (l15 & 7) << 4;
    int cur = 0, nxt2 = 2;
    for (int kt = 0; kt < nk; kt++) {
        if (kt + 2 < nk) stage(nxt2, kt + 2);

        const char* Ab = (const char*)Al[cur];
        const char* Bb = (const char*)Bl[cur];

        bf16x8 bfr[4][2];
        #pragma unroll
        for (int nf = 0; nf < 4; nf++) {
            int rb = wc * 64 + nf * 16 + l15;
            #pragma unroll
            for (int kk = 0; kk < 2; kk++)
                bfr[nf][kk] = *(const bf16x8*)(Bb + rb * 128 + ((kk * 64 + lg * 16) ^ rsw));
        }
        bf16x8 af[4][2];
        #pragma unroll
        for (int mf = 0; mf < 4; mf++) {
            int ra = wr * 64 + mf * 16 + l15;
            #pragma unroll
            for (int kk = 0; kk < 2; kk++)
                af[mf][kk] = *(const bf16x8*)(Ab + ra * 128 + ((kk * 64 + lg * 16) ^ rsw));
        }
        __builtin_amdgcn_s_setprio(1);
        #pragma unroll
        for (int mf = 0; mf < 4; mf++)
            #pragma unroll
            for (int nf = 0; nf < 4; nf++)
                #pragma unroll
                for (int kk = 0; kk < 2; kk++)
                    acc[mf][nf] = __builtin_amdgcn_mfma_f32_16x16x32_bf16(
                        af[mf][kk], bfr[nf][kk], acc[mf][nf], 0, 0, 0);
        __builtin_amdgcn_s_setprio(0);

        // counted drain: tile kt+1 (oldest 6) done; tile kt+2's 6 stay in flight
        if (kt + 2 < nk)      asm volatile("s_waitcnt vmcnt(6)" ::: "memory");
        else if (kt + 1 < nk) asm volatile("s_waitcnt vmcnt(0)" ::: "memory");
        __builtin_amdgcn_s_barrier();

        cur  = (cur  == 2) ? 0 : cur  + 1;
        nxt2 = (nxt2 == 2) ? 0 : nxt2 + 1;
    }

    #pragma unroll
    for (int mi = 0; mi < 4; mi++) {
        #pragma unroll
        for (int nf = 0; nf < 4; nf++) {
            int col = bcol + wc * 64 + nf * 16 + l15;
            float bs = bias[col];
            #pragma unroll
            for (int r = 0; r < 4; r++) {
                int row = brow + wr * 64 + mi * 16 + lg * 4 + r;
                size_t idx = (size_t)row * N + col;
                float v = acc[mi][nf][r] + bs;
                if (EPI == 1) {
                    ((float*)out)[idx] = v + res[idx];
                } else if (EPI == 2) {
                    float u = v + 0.044715f * v * v * v;
                    float e = __builtin_amdgcn_exp2f(-2.3022077f * u);
                    float g = v * __builtin_amdgcn_rcpf(1.0f + e);
                    ((unsigned short*)out)[idx] = f2bf(g);
                } else {
                    unsigned short bv = f2bf(v);
                    ((unsigned short*)out)[idx] = bv;
                    if (col >= 2048) {
                        int hd = col - 2048;
                        int b = row >> 11, s = row & 2047;
                        vtout[((size_t)((b << 4) + (hd >> 6)) * 64 + (hd & 63)) * 2048 + s] = bv;
                    }
                }
            }
        }
    }
}

// ---------------- Flash attention (8-warp, 32x32 swapped, pi-PV) ----
__global__ __launch_bounds__(512, 2) void attn_kernel(
    const unsigned short* __restrict__ qkv, const unsigned short* __restrict__ vt,
    unsigned short* __restrict__ ctx)
{
    __shared__ unsigned short Kl[2][4096];   // [64 keys][64 d], XOR-swizzled rows
    __shared__ unsigned short Vl[2][4096];   // [64 d][64 keys], XOR-swizzled rows

    int t = threadIdx.x;
    int wid = t >> 6, lane = t & 63;
    int l31 = lane & 31, half = lane >> 5;
    int bh = blockIdx.y;
    int b = bh >> 4, h = bh & 15;
    int qr0 = blockIdx.x * 256 + wid * 32;

    const size_t qbase = (size_t)b * 2048 * 3072 + (size_t)h * 64;
    const unsigned short* vbase = vt + (size_t)bh * 64 * 2048;

    bf16x8 qf[4];
    #pragma unroll
    for (int ds = 0; ds < 4; ds++)
        qf[ds] = *(const bf16x8*)(qkv + qbase + (size_t)(qr0 + l31) * 3072 + ds*16 + half*8);

    f32x16 ot0 = {}, ot1 = {};
    float mrun = -1e30f, lrun = 0.0f;
    const float C = 0.125f * 1.44269504f;

    int srow = t >> 3;
    int ssw = ((t & 7) * 16) ^ ((srow & 7) << 4);
    const unsigned short* kg = qkv + qbase + 1024 + (size_t)srow * 3072 + (ssw >> 1);
    const unsigned short* vg = vbase + (size_t)srow * 2048 + (ssw >> 1);

    gload16(kg, (char*)Kl[0] + t * 16);
    gload16(vg, (char*)Vl[0] + t * 16);
    __syncthreads();

    int cur = 0;
    for (int kt = 0; kt < 32; kt++) {
        if (kt < 31) {
            gload16(kg + (size_t)(kt + 1) * 64 * 3072, (char*)Kl[cur ^ 1] + t * 16);
            gload16(vg + (kt + 1) * 64,               (char*)Vl[cur ^ 1] + t * 16);
        }

        const char* Kb = (const char*)Kl[cur];
        const char* Vb = (const char*)Vl[cur];
        int sw = (l31 & 7) << 4;

        // S^T = K . Q^T
        f32x16 st0 = {}, st1 = {};
        __builtin_amdgcn_s_setprio(1);
        #pragma unroll
        for (int ds = 0; ds < 4; ds++) {
            int colb = ds*32 + half*16;
            bf16x8 k0 = *(const bf16x8*)(Kb + l31*128 + (colb ^ sw));
            bf16x8 k1 = *(const bf16x8*)(Kb + (32 + l31)*128 + (colb ^ sw));
            st0 = __builtin_amdgcn_mfma_f32_32x32x16_bf16(k0, qf[ds], st0, 0, 0, 0);
            st1 = __builtin_amdgcn_mfma_f32_32x32x16_bf16(k1, qf[ds], st1, 0, 0, 0);
        }
        __builtin_amdgcn_s_setprio(0);

        float mx = fmaxf(st0[0], st0[1]);
        #pragma unroll
        for (int r = 2; r < 16; r++) mx = fmaxf(mx, st0[r]);
        #pragma unroll
        for (int r = 0; r < 16; r++) mx = fmaxf(mx, st1[r]);
        mx = fmaxf(mx, __shfl_xor(mx, 32));
        float pm = mx * C;

        bool grow = pm > mrun + 11.5416f;
        if (__any(grow)) {
            float mn = fmaxf(mrun, pm);
            float corr = __builtin_amdgcn_exp2f(mrun - mn);
            mrun = mn;
            lrun *= corr;
            ot0 *= corr;
            ot1 *= corr;
        }

        unsigned w0[8], w1[8];
        float sum = 0.0f;
        {
            float e[16];
            #pragma unroll
            for (int r = 0; r < 16; r++) { e[r] = __builtin_amdgcn_exp2f(fmaf(st0[r], C, -mrun)); sum += e[r]; }
            #pragma unroll
            for (int p = 0; p < 8; p++) w0[p] = cvt_pk_bf16(e[2*p], e[2*p+1]);
            #pragma unroll
            for (int r = 0; r < 16; r++) { e[r] = __builtin_amdgcn_exp2f(fmaf(st1[r], C, -mrun)); sum += e[r]; }
            #pragma unroll
            for (int p = 0; p < 8; p++) w1[p] = cvt_pk_bf16(e[2*p], e[2*p+1]);
        }
        lrun += sum;

        // O^T += V^T . P^T with per-MFMA key permutation pi (no lane exchange)
        __builtin_amdgcn_s_setprio(1);
        #pragma unroll
        for (int ks = 0; ks < 4; ks++) {
            union { unsigned u[4]; bf16x8 v; } pf;
            unsigned* w = (ks < 2) ? w0 : w1;
            int o4 = (ks & 1) * 4;
            pf.u[0] = w[o4 + 0]; pf.u[1] = w[o4 + 1]; pf.u[2] = w[o4 + 2]; pf.u[3] = w[o4 + 3];
            int lo = ks*32 + half*8;
            union { unsigned long long d[2]; bf16x8 v; } va, vb;
            va.d[0] = *(const unsigned long long*)(Vb + l31*128 + (lo ^ sw));
            va.d[1] = *(const unsigned long long*)(Vb + l31*128 + ((lo + 16) ^ sw));
            vb.d[0] = *(const unsigned long long*)(Vb + (32 + l31)*128 + (lo ^ sw));
            vb.d[1] = *(const unsigned long long*)(Vb + (32 + l31)*128 + ((lo + 16) ^ sw));
            ot0 = __builtin_amdgcn_mfma_f32_32x32x16_bf16(va.v, pf.v, ot0, 0, 0, 0);
            ot1 = __builtin_amdgcn_mfma_f32_32x32x16_bf16(vb.v, pf.v, ot1, 0, 0, 0);
        }
        __builtin_amdgcn_s_setprio(0);

        __syncthreads();
        cur ^= 1;
    }

    float ltot = lrun + __shfl_xor(lrun, 32);
    float rl = 1.0f / ltot;
    size_t cb = (size_t)b * 2048 * 1024 + (size_t)(qr0 + l31) * 1024 + (size_t)h * 64;
    #pragma unroll
    for (int r = 0; r < 16; r++) {
        int d = (r & 3) + 8 * (r >> 2) + 4 * half;
        ctx[cb + d]      = f2bf(ot0[r] * rl);
        ctx[cb + 32 + d] = f2bf(ot1[r] * rl);
    }
}

// ---------------- launch ----------------
extern "C" void kernel_launch(void* const* d_in, const int* in_sizes, int n_in,
                              void* d_out, int out_size, void* d_ws, size_t ws_size,
                              hipStream_t stream) {
    const float* x      = (const float*)d_in[0];
    const float* ln1_s  = (const float*)d_in[1];
    const float* ln1_b  = (const float*)d_in[2];
    const float* ln2_s  = (const float*)d_in[3];
    const float* ln2_b  = (const float*)d_in[4];
    const float* qkv_w  = (const float*)d_in[5];
    const float* qkv_b  = (const float*)d_in[6];
    const float* proj_w = (const float*)d_in[7];
    const float* proj_b = (const float*)d_in[8];
    const float* fc1_w  = (const float*)d_in[9];
    const float* fc1_b  = (const float*)d_in[10];
    const float* fc2_w  = (const float*)d_in[11];
    const float* fc2_b  = (const float*)d_in[12];
    float* out = (float*)d_out;

    char* ws = (char*)d_ws;
    unsigned short* vtb  = (unsigned short*)(ws + 0);
    float*          x1   = (float*)(ws + 0);
    unsigned short* h    = (unsigned short*)(ws + (size_t)32 * 1024 * 1024);
    unsigned short* qkvb = (unsigned short*)(ws + (size_t)48 * 1024 * 1024);
    unsigned short* gbuf = (unsigned short*)(ws + (size_t)48 * 1024 * 1024);
    unsigned short* ctxb = (unsigned short*)(ws + (size_t)96 * 1024 * 1024);
    unsigned short* wT   = (unsigned short*)(ws + (size_t)112 * 1024 * 1024);

    dim3 tb(32, 8);

    // 1) qkv_w^T
    transpose_kernel<<<dim3(96, 32), tb, 0, stream>>>(qkv_w, wT, 1024, 3072);
    // 2) h = LN1(x)
    ln_kernel<<<8192, 256, 0, stream>>>(x, ln1_s, ln1_b, h);
    // 3) qkv = h @ qkv_w + b   (+ V^T scatter)   grid 24x32 = 768
    gemm256_kernel<3><<<dim3(24, 32), 512, 0, stream>>>(h, wT, qkv_b, nullptr, qkvb, vtb, 8192, 3072, 1024);
    // 4) attention (8-warp 32x32)
    attn_kernel<<<dim3(8, 64), 512, 0, stream>>>(qkvb, vtb, ctxb);
    // 5) proj_w^T
    transpose_kernel<<<dim3(32, 32), tb, 0, stream>>>(proj_w, wT, 1024, 1024);
    // 6) x1 = x + ctx @ proj_w + b   grid 8x32 = 256
    gemm256_kernel<1><<<dim3(8, 32), 512, 0, stream>>>(ctxb, wT, proj_b, x, x1, nullptr, 8192, 1024, 1024);
    // 7) h = LN2(x1)
    ln_kernel<<<8192, 256, 0, stream>>>(x1, ln2_s, ln2_b, h);
    // 8) fc1_w^T
    transpose_kernel<<<dim3(128, 32), tb, 0, stream>>>(fc1_w, wT, 1024, 4096);
    // 9) g = gelu(h @ fc1_w + b)   grid 32x32 = 1024
    gemm256_kernel<2><<<dim3(32, 32), 512, 0, stream>>>(h, wT, fc1_b, nullptr, gbuf, nullptr, 8192, 4096, 1024);
    // 10) fc2_w^T
    transpose_kernel<<<dim3(32, 128), tb, 0, stream>>>(fc2_w, wT, 4096, 1024);
    // 11) out = x1 + g @ fc2_w + b   grid 8x32 = 256
    gemm256_kernel<1><<<dim3(8, 32), 512, 0, stream>>>(gbuf, wT, fc2_b, x1, out, nullptr, 8192, 1024, 4096);
}

// Round 9
// 416.221 us; speedup vs baseline: 1.0730x; 1.0730x over previous
//
#include <hip/hip_runtime.h>
#include <hip/hip_bf16.h>

typedef __attribute__((ext_vector_type(4))) float f32x4;
typedef __attribute__((ext_vector_type(16))) float f32x16;
typedef __attribute__((ext_vector_type(8))) short bf16x8;

__device__ __forceinline__ unsigned short f2bf(float f) {
    return __bfloat16_as_ushort(__float2bfloat16(f));
}

typedef __attribute__((address_space(1))) const unsigned char* gas_ptr;
typedef __attribute__((address_space(3))) unsigned char* las_ptr;
__device__ __forceinline__ void gload16(const void* g, void* l) {
    __builtin_amdgcn_global_load_lds((gas_ptr)g, (las_ptr)l, 16, 0, 0);
}

__device__ __forceinline__ unsigned cvt_pk_bf16(float lo, float hi) {
    unsigned r;
    asm("v_cvt_pk_bf16_f32 %0, %1, %2" : "=v"(r) : "v"(lo), "v"(hi));
    return r;
}

// ---------------- LayerNorm: fp32 in -> bf16 out -------------------
__global__ __launch_bounds__(256) void ln_kernel(
    const float* __restrict__ x, const float* __restrict__ scale,
    const float* __restrict__ bias, unsigned short* __restrict__ out)
{
    int row = blockIdx.x;
    const float* xr = x + (size_t)row * 1024;
    int t = threadIdx.x;
    float4 v = ((const float4*)xr)[t];
    float s  = v.x + v.y + v.z + v.w;
    float ss = v.x*v.x + v.y*v.y + v.z*v.z + v.w*v.w;
    #pragma unroll
    for (int m = 32; m; m >>= 1) { s += __shfl_down(s, m); ss += __shfl_down(ss, m); }
    __shared__ float red[8];
    int wid = t >> 6;
    if ((t & 63) == 0) { red[wid*2] = s; red[wid*2+1] = ss; }
    __syncthreads();
    s  = red[0] + red[2] + red[4] + red[6];
    ss = red[1] + red[3] + red[5] + red[7];
    float mu  = s * (1.0f/1024.0f);
    float var = ss * (1.0f/1024.0f) - mu*mu;
    float inv = rsqrtf(var + 1e-6f);
    float4 sc = ((const float4*)scale)[t];
    float4 bi = ((const float4*)bias)[t];
    ushort4 o;
    o.x = f2bf((v.x - mu)*inv*sc.x + bi.x);
    o.y = f2bf((v.y - mu)*inv*sc.y + bi.y);
    o.z = f2bf((v.z - mu)*inv*sc.z + bi.z);
    o.w = f2bf((v.w - mu)*inv*sc.w + bi.w);
    ((ushort4*)(out + (size_t)row * 1024))[t] = o;
}

// ---------------- Weight transpose: fp32 [K][N] -> bf16 [N][K] -----
__global__ __launch_bounds__(256) void transpose_kernel(
    const float* __restrict__ W, unsigned short* __restrict__ Wt, int K, int N)
{
    __shared__ float tile[32][33];
    int n0 = blockIdx.x * 32, k0 = blockIdx.y * 32;
    int tx = threadIdx.x, ty = threadIdx.y;
    #pragma unroll
    for (int j = 0; j < 32; j += 8)
        tile[ty + j][tx] = W[(size_t)(k0 + ty + j) * N + n0 + tx];
    __syncthreads();
    #pragma unroll
    for (int j = 0; j < 32; j += 8)
        Wt[(size_t)(n0 + ty + j) * K + k0 + tx] = f2bf(tile[tx][ty + j]);
}

// ===== 4-PHASE GEMM, 256x256 tile, swizzled LDS, counted vmcnt =====
// C = A[M,K](bf16) @ Bt[N,K](bf16)^T + bias
// 8 waves 2Mx4N (wave tile 128x64). Per K-tile: 4 phases (kk,mhalf).
// Staging: 8 slab-loads/iter spread 2/phase; vmcnt(2) at ph1 (retire prev
// A1,A3 before ph2 reads) and ph4 (retire B0-3,A0,A2 before next ph1),
// each BEFORE a barrier so all waves' loads are visible.
template<int EPI>
__global__ __launch_bounds__(512, 2) void gemm4p_kernel(
    const unsigned short* __restrict__ A,
    const unsigned short* __restrict__ Bt,
    const float* __restrict__ bias,
    const float* __restrict__ res,
    void* __restrict__ out,
    unsigned short* __restrict__ vtout,
    int M, int N, int K)
{
    __shared__ __align__(16) unsigned short Al[2][256 * 64];   // 64 KB
    __shared__ __align__(16) unsigned short Bl[2][256 * 64];   // 64 KB

    int t = threadIdx.x;
    int wid = t >> 6, lane = t & 63;
    int wr = wid >> 2, wc = wid & 3;          // 2M x 4N
    int l15 = lane & 15, lg = lane >> 4;

    int gx = gridDim.x;
    int nwg = gx * gridDim.y;
    int orig = blockIdx.y * gx + blockIdx.x;
    int cpx = nwg >> 3;
    int wg = (orig & 7) * cpx + (orig >> 3);
    int bx = wg % gx, by = wg / gx;
    int brow = by * 256, bcol = bx * 256;

    f32x4 acc[8][4] = {};

    // staging geometry: one gload16 by 512 threads = 8 KB slab = 64 rows
    int sr  = t >> 3;                        // row within slab (0..63)
    int scb = (t & 7) * 16;                  // byte col
    int sce = (scb ^ ((sr & 7) << 4)) >> 1;  // pre-swizzled source col (elems)
    const size_t aoff = (size_t)(brow + sr) * K + sce;
    const size_t boff = (size_t)(bcol + sr) * K + sce;

    auto stgA = [&](int b, int kt2, int s0, int s1) {
        int k0 = kt2 << 6;
        char* la = (char*)Al[b] + (wid << 10);
        gload16(A + aoff + (size_t)(s0 * 64) * K + k0, la + s0 * 8192);
        gload16(A + aoff + (size_t)(s1 * 64) * K + k0, la + s1 * 8192);
    };
    auto stgB = [&](int b, int kt2, int s0, int s1) {
        int k0 = kt2 << 6;
        char* lb = (char*)Bl[b] + (wid << 10);
        gload16(Bt + boff + (size_t)(s0 * 64) * K + k0, lb + s0 * 8192);
        gload16(Bt + boff + (size_t)(s1 * 64) * K + k0, lb + s1 * 8192);
    };

    int nk = K >> 6;
    // prologue: full tile 0
    stgB(0, 0, 0, 1); stgB(0, 0, 2, 3);
    stgA(0, 0, 0, 2); stgA(0, 0, 1, 3);
    asm volatile("s_waitcnt vmcnt(0)" ::: "memory");
    __builtin_amdgcn_s_barrier();

    int rsw = (l15 & 7) << 4;
    for (int kt = 0; kt < nk; kt++) {
        int cur = kt & 1, nxt = cur ^ 1;
        bool st = (kt + 1 < nk);
        const char* Ab = (const char*)Al[cur];
        const char* Bb = (const char*)Bl[cur];
        bf16x8 bfr[4], af[4];

        // ---- phase 1: kk=0, m-half 0 ----
        #pragma unroll
        for (int nf = 0; nf < 4; nf++) {
            int rb = wc * 64 + nf * 16 + l15;
            bfr[nf] = *(const bf16x8*)(Bb + rb * 128 + ((lg * 16) ^ rsw));
        }
        #pragma unroll
        for (int mf = 0; mf < 4; mf++) {
            int ra = wr * 128 + mf * 16 + l15;
            af[mf] = *(const bf16x8*)(Ab + ra * 128 + ((lg * 16) ^ rsw));
        }
        if (st) stgB(nxt, kt + 1, 0, 1);
        if (st) asm volatile("s_waitcnt vmcnt(2)" ::: "memory");   // retire prev A1,A3
        else    asm volatile("s_waitcnt vmcnt(0)" ::: "memory");
        __builtin_amdgcn_sched_barrier(0);
        __builtin_amdgcn_s_barrier();
        asm volatile("s_waitcnt lgkmcnt(0)" ::: "memory");
        __builtin_amdgcn_sched_barrier(0);
        __builtin_amdgcn_s_setprio(1);
        #pragma unroll
        for (int mf = 0; mf < 4; mf++)
            #pragma unroll
            for (int nf = 0; nf < 4; nf++)
                acc[mf][nf] = __builtin_amdgcn_mfma_f32_16x16x32_bf16(af[mf], bfr[nf], acc[mf][nf], 0, 0, 0);
        __builtin_amdgcn_s_setprio(0);
        __builtin_amdgcn_s_barrier();

        // ---- phase 2: kk=0, m-half 1 ----
        #pragma unroll
        for (int mf = 0; mf < 4; mf++) {
            int ra = wr * 128 + 64 + mf * 16 + l15;
            af[mf] = *(const bf16x8*)(Ab + ra * 128 + ((lg * 16) ^ rsw));
        }
        if (st) stgB(nxt, kt + 1, 2, 3);
        __builtin_amdgcn_sched_barrier(0);
        __builtin_amdgcn_s_barrier();
        asm volatile("s_waitcnt lgkmcnt(0)" ::: "memory");
        __builtin_amdgcn_sched_barrier(0);
        __builtin_amdgcn_s_setprio(1);
        #pragma unroll
        for (int mf = 0; mf < 4; mf++)
            #pragma unroll
            for (int nf = 0; nf < 4; nf++)
                acc[4 + mf][nf] = __builtin_amdgcn_mfma_f32_16x16x32_bf16(af[mf], bfr[nf], acc[4 + mf][nf], 0, 0, 0);
        __builtin_amdgcn_s_setprio(0);
        __builtin_amdgcn_s_barrier();

        // ---- phase 3: kk=1, m-half 0 ----
        #pragma unroll
        for (int nf = 0; nf < 4; nf++) {
            int rb = wc * 64 + nf * 16 + l15;
            bfr[nf] = *(const bf16x8*)(Bb + rb * 128 + ((64 + lg * 16) ^ rsw));
        }
        #pragma unroll
        for (int mf = 0; mf < 4; mf++) {
            int ra = wr * 128 + mf * 16 + l15;
            af[mf] = *(const bf16x8*)(Ab + ra * 128 + ((64 + lg * 16) ^ rsw));
        }
        if (st) stgA(nxt, kt + 1, 0, 2);
        __builtin_amdgcn_sched_barrier(0);
        __builtin_amdgcn_s_barrier();
        asm volatile("s_waitcnt lgkmcnt(0)" ::: "memory");
        __builtin_amdgcn_sched_barrier(0);
        __builtin_amdgcn_s_setprio(1);
        #pragma unroll
        for (int mf = 0; mf < 4; mf++)
            #pragma unroll
            for (int nf = 0; nf < 4; nf++)
                acc[mf][nf] = __builtin_amdgcn_mfma_f32_16x16x32_bf16(af[mf], bfr[nf], acc[mf][nf], 0, 0, 0);
        __builtin_amdgcn_s_setprio(0);
        __builtin_amdgcn_s_barrier();

        // ---- phase 4: kk=1, m-half 1 ----
        #pragma unroll
        for (int mf = 0; mf < 4; mf++) {
            int ra = wr * 128 + 64 + mf * 16 + l15;
            af[mf] = *(const bf16x8*)(Ab + ra * 128 + ((64 + lg * 16) ^ rsw));
        }
        if (st) {
            stgA(nxt, kt + 1, 1, 3);
            asm volatile("s_waitcnt vmcnt(2)" ::: "memory");   // retire B0-3,A0,A2
        }
        __builtin_amdgcn_sched_barrier(0);
        __builtin_amdgcn_s_barrier();
        asm volatile("s_waitcnt lgkmcnt(0)" ::: "memory");
        __builtin_amdgcn_sched_barrier(0);
        __builtin_amdgcn_s_setprio(1);
        #pragma unroll
        for (int mf = 0; mf < 4; mf++)
            #pragma unroll
            for (int nf = 0; nf < 4; nf++)
                acc[4 + mf][nf] = __builtin_amdgcn_mfma_f32_16x16x32_bf16(af[mf], bfr[nf], acc[4 + mf][nf], 0, 0, 0);
        __builtin_amdgcn_s_setprio(0);
        __builtin_amdgcn_s_barrier();
    }

    // epilogue: wave tile 128x64 (mi 0..7)
    #pragma unroll
    for (int mi = 0; mi < 8; mi++) {
        #pragma unroll
        for (int nf = 0; nf < 4; nf++) {
            int col = bcol + wc * 64 + nf * 16 + l15;
            float bs = bias[col];
            #pragma unroll
            for (int r = 0; r < 4; r++) {
                int row = brow + wr * 128 + mi * 16 + lg * 4 + r;
                size_t idx = (size_t)row * N + col;
                float v = acc[mi][nf][r] + bs;
                if (EPI == 1) {
                    ((float*)out)[idx] = v + res[idx];
                } else if (EPI == 2) {
                    float u = v + 0.044715f * v * v * v;
                    float e = __builtin_amdgcn_exp2f(-2.3022077f * u);
                    float g = v * __builtin_amdgcn_rcpf(1.0f + e);
                    ((unsigned short*)out)[idx] = f2bf(g);
                } else {
                    unsigned short bv = f2bf(v);
                    ((unsigned short*)out)[idx] = bv;
                    if (col >= 2048) {
                        int hd = col - 2048;
                        int b = row >> 11, s = row & 2047;
                        vtout[((size_t)((b << 4) + (hd >> 6)) * 64 + (hd & 63)) * 2048 + s] = bv;
                    }
                }
            }
        }
    }
}

// ------- GEMM 256x128 tile, swizzled LDS, 2-phase dbuf (R7) -------
template<int EPI>
__global__ __launch_bounds__(512, 2) void gemm256_kernel(
    const unsigned short* __restrict__ A,
    const unsigned short* __restrict__ Bt,
    const float* __restrict__ bias,
    const float* __restrict__ res,
    void* __restrict__ out,
    unsigned short* __restrict__ vtout,
    int M, int N, int K)
{
    __shared__ __align__(16) unsigned short Al[2][256 * 64];
    __shared__ __align__(16) unsigned short Bl[2][128 * 64];

    int t = threadIdx.x;
    int wid = t >> 6, lane = t & 63;
    int wr = wid >> 1, wc = wid & 1;
    int l15 = lane & 15, lg = lane >> 4;

    int gx = gridDim.x;
    int nwg = gx * gridDim.y;
    int orig = blockIdx.y * gx + blockIdx.x;
    int cpx = nwg >> 3;
    int wg = (orig & 7) * cpx + (orig >> 3);
    int bx = wg % gx, by = wg / gx;
    int brow = by * 256, bcol = bx * 128;

    f32x4 acc[4][4] = {};

    int sr  = t >> 3;
    int scb = (t & 7) * 16;
    int sce = (scb ^ ((sr & 7) << 4)) >> 1;
    const size_t aoff = (size_t)(brow + sr) * K + sce;
    const size_t boff = (size_t)(bcol + sr) * K + sce;

    auto stage = [&](int b, int kt2) {
        int k0 = kt2 << 6;
        char* la = (char*)Al[b] + (wid << 10);
        char* lb = (char*)Bl[b] + (wid << 10);
        #pragma unroll
        for (int i = 0; i < 4; i++)
            gload16(A + aoff + (size_t)(i * 64) * K + k0, la + i * 8192);
        #pragma unroll
        for (int j = 0; j < 2; j++)
            gload16(Bt + boff + (size_t)(j * 64) * K + k0, lb + j * 8192);
    };

    stage(0, 0);
    asm volatile("s_waitcnt vmcnt(0)" ::: "memory");
    __builtin_amdgcn_s_barrier();

    int nk = K >> 6;
    int rsw = (l15 & 7) << 4;
    for (int kt = 0; kt < nk; kt++) {
        int cur = kt & 1;
        if (kt + 1 < nk) stage(cur ^ 1, kt + 1);

        const char* Ab = (const char*)Al[cur];
        const char* Bb = (const char*)Bl[cur];

        bf16x8 bfr[4][2];
        #pragma unroll
        for (int nf = 0; nf < 4; nf++) {
            int rb = wc * 64 + nf * 16 + l15;
            #pragma unroll
            for (int kk = 0; kk < 2; kk++)
                bfr[nf][kk] = *(const bf16x8*)(Bb + rb * 128 + ((kk * 64 + lg * 16) ^ rsw));
        }
        bf16x8 af[4][2];
        #pragma unroll
        for (int mf = 0; mf < 4; mf++) {
            int ra = wr * 64 + mf * 16 + l15;
            #pragma unroll
            for (int kk = 0; kk < 2; kk++)
                af[mf][kk] = *(const bf16x8*)(Ab + ra * 128 + ((kk * 64 + lg * 16) ^ rsw));
        }
        __builtin_amdgcn_s_setprio(1);
        #pragma unroll
        for (int mf = 0; mf < 4; mf++)
            #pragma unroll
            for (int nf = 0; nf < 4; nf++)
                #pragma unroll
                for (int kk = 0; kk < 2; kk++)
                    acc[mf][nf] = __builtin_amdgcn_mfma_f32_16x16x32_bf16(
                        af[mf][kk], bfr[nf][kk], acc[mf][nf], 0, 0, 0);
        __builtin_amdgcn_s_setprio(0);

        asm volatile("s_waitcnt vmcnt(0)" ::: "memory");
        __builtin_amdgcn_s_barrier();
    }

    #pragma unroll
    for (int mi = 0; mi < 4; mi++) {
        #pragma unroll
        for (int nf = 0; nf < 4; nf++) {
            int col = bcol + wc * 64 + nf * 16 + l15;
            float bs = bias[col];
            #pragma unroll
            for (int r = 0; r < 4; r++) {
                int row = brow + wr * 64 + mi * 16 + lg * 4 + r;
                size_t idx = (size_t)row * N + col;
                float v = acc[mi][nf][r] + bs;
                if (EPI == 1) {
                    ((float*)out)[idx] = v + res[idx];
                } else if (EPI == 2) {
                    float u = v + 0.044715f * v * v * v;
                    float e = __builtin_amdgcn_exp2f(-2.3022077f * u);
                    float g = v * __builtin_amdgcn_rcpf(1.0f + e);
                    ((unsigned short*)out)[idx] = f2bf(g);
                } else {
                    unsigned short bv = f2bf(v);
                    ((unsigned short*)out)[idx] = bv;
                    if (col >= 2048) {
                        int hd = col - 2048;
                        int b = row >> 11, s = row & 2047;
                        vtout[((size_t)((b << 4) + (hd >> 6)) * 64 + (hd & 63)) * 2048 + s] = bv;
                    }
                }
            }
        }
    }
}

// ---------------- Flash attention (8-warp, 32x32 swapped, pi-PV) ----
__global__ __launch_bounds__(512, 2) void attn_kernel(
    const unsigned short* __restrict__ qkv, const unsigned short* __restrict__ vt,
    unsigned short* __restrict__ ctx)
{
    __shared__ unsigned short Kl[2][4096];
    __shared__ unsigned short Vl[2][4096];

    int t = threadIdx.x;
    int wid = t >> 6, lane = t & 63;
    int l31 = lane & 31, half = lane >> 5;
    int bh = blockIdx.y;
    int b = bh >> 4, h = bh & 15;
    int qr0 = blockIdx.x * 256 + wid * 32;

    const size_t qbase = (size_t)b * 2048 * 3072 + (size_t)h * 64;
    const unsigned short* vbase = vt + (size_t)bh * 64 * 2048;

    bf16x8 qf[4];
    #pragma unroll
    for (int ds = 0; ds < 4; ds++)
        qf[ds] = *(const bf16x8*)(qkv + qbase + (size_t)(qr0 + l31) * 3072 + ds*16 + half*8);

    f32x16 ot0 = {}, ot1 = {};
    float mrun = -1e30f, lrun = 0.0f;
    const float C = 0.125f * 1.44269504f;

    int srow = t >> 3;
    int ssw = ((t & 7) * 16) ^ ((srow & 7) << 4);
    const unsigned short* kg = qkv + qbase + 1024 + (size_t)srow * 3072 + (ssw >> 1);
    const unsigned short* vg = vbase + (size_t)srow * 2048 + (ssw >> 1);

    gload16(kg, (char*)Kl[0] + t * 16);
    gload16(vg, (char*)Vl[0] + t * 16);
    __syncthreads();

    int cur = 0;
    for (int kt = 0; kt < 32; kt++) {
        if (kt < 31) {
            gload16(kg + (size_t)(kt + 1) * 64 * 3072, (char*)Kl[cur ^ 1] + t * 16);
            gload16(vg + (kt + 1) * 64,               (char*)Vl[cur ^ 1] + t * 16);
        }

        const char* Kb = (const char*)Kl[cur];
        const char* Vb = (const char*)Vl[cur];
        int sw = (l31 & 7) << 4;

        f32x16 st0 = {}, st1 = {};
        __builtin_amdgcn_s_setprio(1);
        #pragma unroll
        for (int ds = 0; ds < 4; ds++) {
            int colb = ds*32 + half*16;
            bf16x8 k0 = *(const bf16x8*)(Kb + l31*128 + (colb ^ sw));
            bf16x8 k1 = *(const bf16x8*)(Kb + (32 + l31)*128 + (colb ^ sw));
            st0 = __builtin_amdgcn_mfma_f32_32x32x16_bf16(k0, qf[ds], st0, 0, 0, 0);
            st1 = __builtin_amdgcn_mfma_f32_32x32x16_bf16(k1, qf[ds], st1, 0, 0, 0);
        }
        __builtin_amdgcn_s_setprio(0);

        float mx = fmaxf(st0[0], st0[1]);
        #pragma unroll
        for (int r = 2; r < 16; r++) mx = fmaxf(mx, st0[r]);
        #pragma unroll
        for (int r = 0; r < 16; r++) mx = fmaxf(mx, st1[r]);
        mx = fmaxf(mx, __shfl_xor(mx, 32));
        float pm = mx * C;

        bool grow = pm > mrun + 11.5416f;
        if (__any(grow)) {
            float mn = fmaxf(mrun, pm);
            float corr = __builtin_amdgcn_exp2f(mrun - mn);
            mrun = mn;
            lrun *= corr;
            ot0 *= corr;
            ot1 *= corr;
        }

        unsigned w0[8], w1[8];
        float sum = 0.0f;
        {
            float e[16];
            #pragma unroll
            for (int r = 0; r < 16; r++) { e[r] = __builtin_amdgcn_exp2f(fmaf(st0[r], C, -mrun)); sum += e[r]; }
            #pragma unroll
            for (int p = 0; p < 8; p++) w0[p] = cvt_pk_bf16(e[2*p], e[2*p+1]);
            #pragma unroll
            for (int r = 0; r < 16; r++) { e[r] = __builtin_amdgcn_exp2f(fmaf(st1[r], C, -mrun)); sum += e[r]; }
            #pragma unroll
            for (int p = 0; p < 8; p++) w1[p] = cvt_pk_bf16(e[2*p], e[2*p+1]);
        }
        lrun += sum;

        __builtin_amdgcn_s_setprio(1);
        #pragma unroll
        for (int ks = 0; ks < 4; ks++) {
            union { unsigned u[4]; bf16x8 v; } pf;
            unsigned* w = (ks < 2) ? w0 : w1;
            int o4 = (ks & 1) * 4;
            pf.u[0] = w[o4 + 0]; pf.u[1] = w[o4 + 1]; pf.u[2] = w[o4 + 2]; pf.u[3] = w[o4 + 3];
            int lo = ks*32 + half*8;
            union { unsigned long long d[2]; bf16x8 v; } va, vb;
            va.d[0] = *(const unsigned long long*)(Vb + l31*128 + (lo ^ sw));
            va.d[1] = *(const unsigned long long*)(Vb + l31*128 + ((lo + 16) ^ sw));
            vb.d[0] = *(const unsigned long long*)(Vb + (32 + l31)*128 + (lo ^ sw));
            vb.d[1] = *(const unsigned long long*)(Vb + (32 + l31)*128 + ((lo + 16) ^ sw));
            ot0 = __builtin_amdgcn_mfma_f32_32x32x16_bf16(va.v, pf.v, ot0, 0, 0, 0);
            ot1 = __builtin_amdgcn_mfma_f32_32x32x16_bf16(vb.v, pf.v, ot1, 0, 0, 0);
        }
        __builtin_amdgcn_s_setprio(0);

        __syncthreads();
        cur ^= 1;
    }

    float ltot = lrun + __shfl_xor(lrun, 32);
    float rl = 1.0f / ltot;
    size_t cb = (size_t)b * 2048 * 1024 + (size_t)(qr0 + l31) * 1024 + (size_t)h * 64;
    #pragma unroll
    for (int r = 0; r < 16; r++) {
        int d = (r & 3) + 8 * (r >> 2) + 4 * half;
        ctx[cb + d]      = f2bf(ot0[r] * rl);
        ctx[cb + 32 + d] = f2bf(ot1[r] * rl);
    }
}

// ---------------- launch ----------------
extern "C" void kernel_launch(void* const* d_in, const int* in_sizes, int n_in,
                              void* d_out, int out_size, void* d_ws, size_t ws_size,
                              hipStream_t stream) {
    const float* x      = (const float*)d_in[0];
    const float* ln1_s  = (const float*)d_in[1];
    const float* ln1_b  = (const float*)d_in[2];
    const float* ln2_s  = (const float*)d_in[3];
    const float* ln2_b  = (const float*)d_in[4];
    const float* qkv_w  = (const float*)d_in[5];
    const float* qkv_b  = (const float*)d_in[6];
    const float* proj_w = (const float*)d_in[7];
    const float* proj_b = (const float*)d_in[8];
    const float* fc1_w  = (const float*)d_in[9];
    const float* fc1_b  = (const float*)d_in[10];
    const float* fc2_w  = (const float*)d_in[11];
    const float* fc2_b  = (const float*)d_in[12];
    float* out = (float*)d_out;

    char* ws = (char*)d_ws;
    unsigned short* vtb  = (unsigned short*)(ws + 0);
    float*          x1   = (float*)(ws + 0);
    unsigned short* h    = (unsigned short*)(ws + (size_t)32 * 1024 * 1024);
    unsigned short* qkvb = (unsigned short*)(ws + (size_t)48 * 1024 * 1024);
    unsigned short* gbuf = (unsigned short*)(ws + (size_t)48 * 1024 * 1024);
    unsigned short* ctxb = (unsigned short*)(ws + (size_t)96 * 1024 * 1024);
    unsigned short* wT   = (unsigned short*)(ws + (size_t)112 * 1024 * 1024);

    dim3 tb(32, 8);

    // 1) qkv_w^T
    transpose_kernel<<<dim3(96, 32), tb, 0, stream>>>(qkv_w, wT, 1024, 3072);
    // 2) h = LN1(x)
    ln_kernel<<<8192, 256, 0, stream>>>(x, ln1_s, ln1_b, h);
    // 3) qkv = h @ qkv_w + b   (+ V^T scatter)   grid 12x32 = 384 (4-phase 256²)
    gemm4p_kernel<3><<<dim3(12, 32), 512, 0, stream>>>(h, wT, qkv_b, nullptr, qkvb, vtb, 8192, 3072, 1024);
    // 4) attention (8-warp 32x32)
    attn_kernel<<<dim3(8, 64), 512, 0, stream>>>(qkvb, vtb, ctxb);
    // 5) proj_w^T
    transpose_kernel<<<dim3(32, 32), tb, 0, stream>>>(proj_w, wT, 1024, 1024);
    // 6) x1 = x + ctx @ proj_w + b   grid 8x32 = 256 (2-phase)
    gemm256_kernel<1><<<dim3(8, 32), 512, 0, stream>>>(ctxb, wT, proj_b, x, x1, nullptr, 8192, 1024, 1024);
    // 7) h = LN2(x1)
    ln_kernel<<<8192, 256, 0, stream>>>(x1, ln2_s, ln2_b, h);
    // 8) fc1_w^T
    transpose_kernel<<<dim3(128, 32), tb, 0, stream>>>(fc1_w, wT, 1024, 4096);
    // 9) g = gelu(h @ fc1_w + b)   grid 16x32 = 512 (4-phase 256²)
    gemm4p_kernel<2><<<dim3(16, 32), 512, 0, stream>>>(h, wT, fc1_b, nullptr, gbuf, nullptr, 8192, 4096, 1024);
    // 10) fc2_w^T
    transpose_kernel<<<dim3(32, 128), tb, 0, stream>>>(fc2_w, wT, 4096, 1024);
    // 11) out = x1 + g @ fc2_w + b   grid 8x32 = 256 (2-phase)
    gemm256_kernel<1><<<dim3(8, 32), 512, 0, stream>>>(gbuf, wT, fc2_b, x1, out, nullptr, 8192, 1024, 4096);
}

// Round 10
// 396.677 us; speedup vs baseline: 1.1258x; 1.0493x over previous
//
#include <hip/hip_runtime.h>
#include <hip/hip_bf16.h>

typedef __attribute__((ext_vector_type(4))) float f32x4;
typedef __attribute__((ext_vector_type(16))) float f32x16;
typedef __attribute__((ext_vector_type(8))) short bf16x8;

__device__ __forceinline__ unsigned short f2bf(float f) {
    return __bfloat16_as_ushort(__float2bfloat16(f));
}

typedef __attribute__((address_space(1))) const unsigned char* gas_ptr;
typedef __attribute__((address_space(3))) unsigned char* las_ptr;
__device__ __forceinline__ void gload16(const void* g, void* l) {
    __builtin_amdgcn_global_load_lds((gas_ptr)g, (las_ptr)l, 16, 0, 0);
}

__device__ __forceinline__ unsigned cvt_pk_bf16(float lo, float hi) {
    unsigned r;
    asm("v_cvt_pk_bf16_f32 %0, %1, %2" : "=v"(r) : "v"(lo), "v"(hi));
    return r;
}

// ---------------- LayerNorm: fp32 in -> bf16 out -------------------
__global__ __launch_bounds__(256) void ln_kernel(
    const float* __restrict__ x, const float* __restrict__ scale,
    const float* __restrict__ bias, unsigned short* __restrict__ out)
{
    int row = blockIdx.x;
    const float* xr = x + (size_t)row * 1024;
    int t = threadIdx.x;
    float4 v = ((const float4*)xr)[t];
    float s  = v.x + v.y + v.z + v.w;
    float ss = v.x*v.x + v.y*v.y + v.z*v.z + v.w*v.w;
    #pragma unroll
    for (int m = 32; m; m >>= 1) { s += __shfl_down(s, m); ss += __shfl_down(ss, m); }
    __shared__ float red[8];
    int wid = t >> 6;
    if ((t & 63) == 0) { red[wid*2] = s; red[wid*2+1] = ss; }
    __syncthreads();
    s  = red[0] + red[2] + red[4] + red[6];
    ss = red[1] + red[3] + red[5] + red[7];
    float mu  = s * (1.0f/1024.0f);
    float var = ss * (1.0f/1024.0f) - mu*mu;
    float inv = rsqrtf(var + 1e-6f);
    float4 sc = ((const float4*)scale)[t];
    float4 bi = ((const float4*)bias)[t];
    ushort4 o;
    o.x = f2bf((v.x - mu)*inv*sc.x + bi.x);
    o.y = f2bf((v.y - mu)*inv*sc.y + bi.y);
    o.z = f2bf((v.z - mu)*inv*sc.z + bi.z);
    o.w = f2bf((v.w - mu)*inv*sc.w + bi.w);
    ((ushort4*)(out + (size_t)row * 1024))[t] = o;
}

// ---------------- Weight transpose: fp32 [K][N] -> bf16 [N][K] -----
__global__ __launch_bounds__(256) void transpose_kernel(
    const float* __restrict__ W, unsigned short* __restrict__ Wt, int K, int N)
{
    __shared__ float tile[32][33];
    int n0 = blockIdx.x * 32, k0 = blockIdx.y * 32;
    int tx = threadIdx.x, ty = threadIdx.y;
    #pragma unroll
    for (int j = 0; j < 32; j += 8)
        tile[ty + j][tx] = W[(size_t)(k0 + ty + j) * N + n0 + tx];
    __syncthreads();
    #pragma unroll
    for (int j = 0; j < 32; j += 8)
        Wt[(size_t)(n0 + ty + j) * K + k0 + tx] = f2bf(tile[tx][ty + j]);
}

// ===== m97-style GEMM: 128x128 tile, 4 waves, single-buffer swizzled LDS =====
// C = A[M,K](bf16) @ Bt[N,K](bf16)^T + bias
// High occupancy (4 blocks/CU) does the pipelining via cross-block overlap.
// EPI 1: fp32 out + residual.  EPI 2: gelu -> bf16.  EPI 3: bf16 + V^T scatter.
template<int EPI>
__global__ __launch_bounds__(256, 4) void gemm_kernel(
    const unsigned short* __restrict__ A,
    const unsigned short* __restrict__ Bt,
    const float* __restrict__ bias,
    const float* __restrict__ res,
    void* __restrict__ out,
    unsigned short* __restrict__ vtout,
    int M, int N, int K)
{
    __shared__ __align__(16) unsigned short Al[128 * 64];   // 16 KB
    __shared__ __align__(16) unsigned short Bl[128 * 64];   // 16 KB

    int t = threadIdx.x;
    int wid = t >> 6, lane = t & 63;
    int wr = wid >> 1, wc = wid & 1;          // 2M x 2N waves, wave tile 64x64
    int l15 = lane & 15, lg = lane >> 4;

    int gx = gridDim.x;
    int nwg = gx * gridDim.y;
    int orig = blockIdx.y * gx + blockIdx.x;
    int cpx = nwg >> 3;
    int wg = (orig & 7) * cpx + (orig >> 3);
    int bx = wg % gx, by = wg / gx;
    int brow = by * 128, bcol = bx * 128;

    f32x4 acc[4][4] = {};

    // staging: 256 threads x 16B = 4 KB slab = 32 rows; 4 slabs per 128-row tile
    int sr  = t >> 3;                        // 0..31 row within slab
    int scb = (t & 7) * 16;                  // byte col
    int sce = (scb ^ ((sr & 7) << 4)) >> 1;  // pre-swizzled source col (elems)
    const size_t aoff = (size_t)(brow + sr) * K + sce;
    const size_t boff = (size_t)(bcol + sr) * K + sce;
    char* la = (char*)Al + (wid << 10);
    char* lb = (char*)Bl + (wid << 10);

    int nk = K >> 6;
    int rsw = (l15 & 7) << 4;
    for (int kt = 0; kt < nk; kt++) {
        int k0 = kt << 6;
        __syncthreads();   // previous tile fully consumed
        #pragma unroll
        for (int i = 0; i < 4; i++) {
            gload16(A  + aoff + (size_t)(i * 32) * K + k0, la + i * 4096);
            gload16(Bt + boff + (size_t)(i * 32) * K + k0, lb + i * 4096);
        }
        __syncthreads();   // compiler drains vmcnt+lgkm before barrier
        #pragma unroll
        for (int kf = 0; kf < 2; kf++) {
            bf16x8 af[4], bfr[4];
            #pragma unroll
            for (int mf = 0; mf < 4; mf++)
                af[mf] = *(const bf16x8*)((const char*)Al + (wr*64 + mf*16 + l15)*128 + ((kf*64 + lg*16) ^ rsw));
            #pragma unroll
            for (int nf = 0; nf < 4; nf++)
                bfr[nf] = *(const bf16x8*)((const char*)Bl + (wc*64 + nf*16 + l15)*128 + ((kf*64 + lg*16) ^ rsw));
            __builtin_amdgcn_s_setprio(1);
            #pragma unroll
            for (int mf = 0; mf < 4; mf++)
                #pragma unroll
                for (int nf = 0; nf < 4; nf++)
                    acc[mf][nf] = __builtin_amdgcn_mfma_f32_16x16x32_bf16(
                        af[mf], bfr[nf], acc[mf][nf], 0, 0, 0);
            __builtin_amdgcn_s_setprio(0);
        }
    }

    // epilogue: wave tile 64x64
    #pragma unroll
    for (int mi = 0; mi < 4; mi++) {
        #pragma unroll
        for (int nf = 0; nf < 4; nf++) {
            int col = bcol + wc * 64 + nf * 16 + l15;
            float bs = bias[col];
            #pragma unroll
            for (int r = 0; r < 4; r++) {
                int row = brow + wr * 64 + mi * 16 + lg * 4 + r;
                size_t idx = (size_t)row * N + col;
                float v = acc[mi][nf][r] + bs;
                if (EPI == 1) {
                    ((float*)out)[idx] = v + res[idx];
                } else if (EPI == 2) {
                    float u = v + 0.044715f * v * v * v;
                    float e = __builtin_amdgcn_exp2f(-2.3022077f * u);
                    float g = v * __builtin_amdgcn_rcpf(1.0f + e);
                    ((unsigned short*)out)[idx] = f2bf(g);
                } else {
                    unsigned short bv = f2bf(v);
                    ((unsigned short*)out)[idx] = bv;
                    if (col >= 2048) {
                        int hd = col - 2048;
                        int b = row >> 11, s = row & 2047;
                        vtout[((size_t)((b << 4) + (hd >> 6)) * 64 + (hd & 63)) * 2048 + s] = bv;
                    }
                }
            }
        }
    }
}

// ---------------- Flash attention (8-warp, 32x32 swapped, pi-PV) ----
__global__ __launch_bounds__(512, 2) void attn_kernel(
    const unsigned short* __restrict__ qkv, const unsigned short* __restrict__ vt,
    unsigned short* __restrict__ ctx)
{
    __shared__ unsigned short Kl[2][4096];
    __shared__ unsigned short Vl[2][4096];

    int t = threadIdx.x;
    int wid = t >> 6, lane = t & 63;
    int l31 = lane & 31, half = lane >> 5;
    int bh = blockIdx.y;
    int b = bh >> 4, h = bh & 15;
    int qr0 = blockIdx.x * 256 + wid * 32;

    const size_t qbase = (size_t)b * 2048 * 3072 + (size_t)h * 64;
    const unsigned short* vbase = vt + (size_t)bh * 64 * 2048;

    bf16x8 qf[4];
    #pragma unroll
    for (int ds = 0; ds < 4; ds++)
        qf[ds] = *(const bf16x8*)(qkv + qbase + (size_t)(qr0 + l31) * 3072 + ds*16 + half*8);

    f32x16 ot0 = {}, ot1 = {};
    float mrun = -1e30f, lrun = 0.0f;
    const float C = 0.125f * 1.44269504f;

    int srow = t >> 3;
    int ssw = ((t & 7) * 16) ^ ((srow & 7) << 4);
    const unsigned short* kg = qkv + qbase + 1024 + (size_t)srow * 3072 + (ssw >> 1);
    const unsigned short* vg = vbase + (size_t)srow * 2048 + (ssw >> 1);

    gload16(kg, (char*)Kl[0] + t * 16);
    gload16(vg, (char*)Vl[0] + t * 16);
    __syncthreads();

    int cur = 0;
    for (int kt = 0; kt < 32; kt++) {
        if (kt < 31) {
            gload16(kg + (size_t)(kt + 1) * 64 * 3072, (char*)Kl[cur ^ 1] + t * 16);
            gload16(vg + (kt + 1) * 64,               (char*)Vl[cur ^ 1] + t * 16);
        }

        const char* Kb = (const char*)Kl[cur];
        const char* Vb = (const char*)Vl[cur];
        int sw = (l31 & 7) << 4;

        f32x16 st0 = {}, st1 = {};
        __builtin_amdgcn_s_setprio(1);
        #pragma unroll
        for (int ds = 0; ds < 4; ds++) {
            int colb = ds*32 + half*16;
            bf16x8 k0 = *(const bf16x8*)(Kb + l31*128 + (colb ^ sw));
            bf16x8 k1 = *(const bf16x8*)(Kb + (32 + l31)*128 + (colb ^ sw));
            st0 = __builtin_amdgcn_mfma_f32_32x32x16_bf16(k0, qf[ds], st0, 0, 0, 0);
            st1 = __builtin_amdgcn_mfma_f32_32x32x16_bf16(k1, qf[ds], st1, 0, 0, 0);
        }
        __builtin_amdgcn_s_setprio(0);

        float mx = fmaxf(st0[0], st0[1]);
        #pragma unroll
        for (int r = 2; r < 16; r++) mx = fmaxf(mx, st0[r]);
        #pragma unroll
        for (int r = 0; r < 16; r++) mx = fmaxf(mx, st1[r]);
        mx = fmaxf(mx, __shfl_xor(mx, 32));
        float pm = mx * C;

        bool grow = pm > mrun + 11.5416f;
        if (__any(grow)) {
            float mn = fmaxf(mrun, pm);
            float corr = __builtin_amdgcn_exp2f(mrun - mn);
            mrun = mn;
            lrun *= corr;
            ot0 *= corr;
            ot1 *= corr;
        }

        unsigned w0[8], w1[8];
        float sum = 0.0f;
        {
            float e[16];
            #pragma unroll
            for (int r = 0; r < 16; r++) { e[r] = __builtin_amdgcn_exp2f(fmaf(st0[r], C, -mrun)); sum += e[r]; }
            #pragma unroll
            for (int p = 0; p < 8; p++) w0[p] = cvt_pk_bf16(e[2*p], e[2*p+1]);
            #pragma unroll
            for (int r = 0; r < 16; r++) { e[r] = __builtin_amdgcn_exp2f(fmaf(st1[r], C, -mrun)); sum += e[r]; }
            #pragma unroll
            for (int p = 0; p < 8; p++) w1[p] = cvt_pk_bf16(e[2*p], e[2*p+1]);
        }
        lrun += sum;

        __builtin_amdgcn_s_setprio(1);
        #pragma unroll
        for (int ks = 0; ks < 4; ks++) {
            union { unsigned u[4]; bf16x8 v; } pf;
            unsigned* w = (ks < 2) ? w0 : w1;
            int o4 = (ks & 1) * 4;
            pf.u[0] = w[o4 + 0]; pf.u[1] = w[o4 + 1]; pf.u[2] = w[o4 + 2]; pf.u[3] = w[o4 + 3];
            int lo = ks*32 + half*8;
            union { unsigned long long d[2]; bf16x8 v; } va, vb;
            va.d[0] = *(const unsigned long long*)(Vb + l31*128 + (lo ^ sw));
            va.d[1] = *(const unsigned long long*)(Vb + l31*128 + ((lo + 16) ^ sw));
            vb.d[0] = *(const unsigned long long*)(Vb + (32 + l31)*128 + (lo ^ sw));
            vb.d[1] = *(const unsigned long long*)(Vb + (32 + l31)*128 + ((lo + 16) ^ sw));
            ot0 = __builtin_amdgcn_mfma_f32_32x32x16_bf16(va.v, pf.v, ot0, 0, 0, 0);
            ot1 = __builtin_amdgcn_mfma_f32_32x32x16_bf16(vb.v, pf.v, ot1, 0, 0, 0);
        }
        __builtin_amdgcn_s_setprio(0);

        __syncthreads();
        cur ^= 1;
    }

    float ltot = lrun + __shfl_xor(lrun, 32);
    float rl = 1.0f / ltot;
    size_t cb = (size_t)b * 2048 * 1024 + (size_t)(qr0 + l31) * 1024 + (size_t)h * 64;
    #pragma unroll
    for (int r = 0; r < 16; r++) {
        int d = (r & 3) + 8 * (r >> 2) + 4 * half;
        ctx[cb + d]      = f2bf(ot0[r] * rl);
        ctx[cb + 32 + d] = f2bf(ot1[r] * rl);
    }
}

// ---------------- launch ----------------
extern "C" void kernel_launch(void* const* d_in, const int* in_sizes, int n_in,
                              void* d_out, int out_size, void* d_ws, size_t ws_size,
                              hipStream_t stream) {
    const float* x      = (const float*)d_in[0];
    const float* ln1_s  = (const float*)d_in[1];
    const float* ln1_b  = (const float*)d_in[2];
    const float* ln2_s  = (const float*)d_in[3];
    const float* ln2_b  = (const float*)d_in[4];
    const float* qkv_w  = (const float*)d_in[5];
    const float* qkv_b  = (const float*)d_in[6];
    const float* proj_w = (const float*)d_in[7];
    const float* proj_b = (const float*)d_in[8];
    const float* fc1_w  = (const float*)d_in[9];
    const float* fc1_b  = (const float*)d_in[10];
    const float* fc2_w  = (const float*)d_in[11];
    const float* fc2_b  = (const float*)d_in[12];
    float* out = (float*)d_out;

    char* ws = (char*)d_ws;
    unsigned short* vtb  = (unsigned short*)(ws + 0);
    float*          x1   = (float*)(ws + 0);
    unsigned short* h    = (unsigned short*)(ws + (size_t)32 * 1024 * 1024);
    unsigned short* qkvb = (unsigned short*)(ws + (size_t)48 * 1024 * 1024);
    unsigned short* gbuf = (unsigned short*)(ws + (size_t)48 * 1024 * 1024);
    unsigned short* ctxb = (unsigned short*)(ws + (size_t)96 * 1024 * 1024);
    unsigned short* wT   = (unsigned short*)(ws + (size_t)112 * 1024 * 1024);

    dim3 tb(32, 8);

    // 1) qkv_w^T
    transpose_kernel<<<dim3(96, 32), tb, 0, stream>>>(qkv_w, wT, 1024, 3072);
    // 2) h = LN1(x)
    ln_kernel<<<8192, 256, 0, stream>>>(x, ln1_s, ln1_b, h);
    // 3) qkv = h @ qkv_w + b   (+ V^T scatter)   grid 24x64 = 1536
    gemm_kernel<3><<<dim3(24, 64), 256, 0, stream>>>(h, wT, qkv_b, nullptr, qkvb, vtb, 8192, 3072, 1024);
    // 4) attention (8-warp 32x32)
    attn_kernel<<<dim3(8, 64), 512, 0, stream>>>(qkvb, vtb, ctxb);
    // 5) proj_w^T
    transpose_kernel<<<dim3(32, 32), tb, 0, stream>>>(proj_w, wT, 1024, 1024);
    // 6) x1 = x + ctx @ proj_w + b   grid 8x64 = 512
    gemm_kernel<1><<<dim3(8, 64), 256, 0, stream>>>(ctxb, wT, proj_b, x, x1, nullptr, 8192, 1024, 1024);
    // 7) h = LN2(x1)
    ln_kernel<<<8192, 256, 0, stream>>>(x1, ln2_s, ln2_b, h);
    // 8) fc1_w^T
    transpose_kernel<<<dim3(128, 32), tb, 0, stream>>>(fc1_w, wT, 1024, 4096);
    // 9) g = gelu(h @ fc1_w + b)   grid 32x64 = 2048
    gemm_kernel<2><<<dim3(32, 64), 256, 0, stream>>>(h, wT, fc1_b, nullptr, gbuf, nullptr, 8192, 4096, 1024);
    // 10) fc2_w^T
    transpose_kernel<<<dim3(32, 128), tb, 0, stream>>>(fc2_w, wT, 4096, 1024);
    // 11) out = x1 + g @ fc2_w + b   grid 8x64 = 512
    gemm_kernel<1><<<dim3(8, 64), 256, 0, stream>>>(gbuf, wT, fc2_b, x1, out, nullptr, 8192, 1024, 4096);
}